// Round 1
// baseline (130.451 us; speedup 1.0000x reference)
//
#include <hip/hip_runtime.h>
#include <hip/hip_bf16.h>
#include <math.h>

// UserHistoryTower on MI355X.
// Pipeline:
//   1) per-user clicked-item lists (count -> exclusive scan -> scatter)
//   2) history_emb[i] = mean of ad[j] over clicked j of user[i] with ts[j] < ts[i]
//      (replaces the 8192x8192 masked matmul: avg ~8 clicked items/user)
//   3) MLP via 3 bf16-MFMA GEMMs (fp32 accumulate), SiLU fused in epilogue
//   4) row L2-normalize (double-normalize == single normalize numerically) + empty-row zero
//
// Workspace usage ~19 MB.

#define N_ROWS  8192
#define D_EMB   128
#define H1_DIM  512
#define H2_DIM  256
#define N_USERS 512

typedef __bf16 bf16;
typedef __bf16 bf16x8 __attribute__((ext_vector_type(8)));
typedef float  floatx4 __attribute__((ext_vector_type(4)));

// ---------- 1a: count clicked items per user ----------
__global__ void k_count(const int* __restrict__ user, const int* __restrict__ clk,
                        int* __restrict__ count) {
    int j = blockIdx.x * blockDim.x + threadIdx.x;
    if (j < N_ROWS && clk[j] != 0) atomicAdd(&count[user[j]], 1);
}

// ---------- 1b: exclusive prefix scan over 512 user counts (1 block, 512 thr) ----------
__global__ void k_scan(const int* __restrict__ count, int* __restrict__ offs,
                       int* __restrict__ cursor) {
    __shared__ int s[N_USERS];
    int t = threadIdx.x;
    int c = count[t];
    s[t] = c;
    __syncthreads();
    for (int d = 1; d < N_USERS; d <<= 1) {
        int v = (t >= d) ? s[t - d] : 0;
        __syncthreads();
        s[t] += v;
        __syncthreads();
    }
    offs[t]   = s[t] - c;   // exclusive
    cursor[t] = s[t] - c;   // scatter cursor (atomically bumped)
}

// ---------- 1c: scatter clicked (ts, idx) into per-user segments ----------
__global__ void k_scatter(const int* __restrict__ user, const int* __restrict__ ts,
                          const int* __restrict__ clk, int* __restrict__ cursor,
                          int* __restrict__ item_ts, int* __restrict__ item_idx) {
    int j = blockIdx.x * blockDim.x + threadIdx.x;
    if (j < N_ROWS && clk[j] != 0) {
        int p = atomicAdd(&cursor[user[j]], 1);
        item_ts[p]  = ts[j];
        item_idx[p] = j;
    }
}

// ---------- 2: history embedding — one block (128 thr) per row ----------
__global__ void k_history(const int* __restrict__ user, const int* __restrict__ ts,
                          const int* __restrict__ offs, const int* __restrict__ count,
                          const int* __restrict__ item_ts, const int* __restrict__ item_idx,
                          const float* __restrict__ ad,
                          bf16* __restrict__ hist, int* __restrict__ empty) {
    int i = blockIdx.x;
    int t = threadIdx.x;              // dim 0..127
    int u    = user[i];
    int myts = ts[i];
    int beg = offs[u], end = beg + count[u];
    float acc = 0.f;
    int cnt = 0;
    for (int p = beg; p < end; ++p) {
        int tj = item_ts[p];          // same addr across block -> broadcast
        if (tj < myts) {              // strict: ties/self excluded (matches ts[i] > ts[j])
            ++cnt;
            acc += ad[item_idx[p] * D_EMB + t];   // coalesced 512B row read
        }
    }
    float inv = (cnt > 0) ? 1.0f / (float)cnt : 0.f;  // ref: /(cnt + 1e-16)
    hist[i * D_EMB + t] = (bf16)(acc * inv);
    if (t == 0) empty[i] = (cnt == 0) ? 1 : 0;
}

// ---------- 3: bf16 MFMA GEMM: out[M,NT] = act(A[M,K] @ W[K,NT] + bias) ----------
// Block = 256 thr (4 waves), tile 64(M) x 64(N). Wave w owns cols [w*16, w*16+16).
// Per 32-wide K-chunk: stage A(64x32) and W^T(64x32, f32->bf16, transposed) in LDS,
// then 4 MFMA per wave (16x16x32), fragments are contiguous 16B ds_read_b128.
// Layouts (HW-verified, learn_hip m89/m91/m120):
//   A-op:  lane holds A[m=lane&15][k=(lane>>4)*8 + j]
//   B-op:  lane holds B[k=(lane>>4)*8 + j][n=lane&15]   (read from transposed LDS tile)
//   C/D:   lane,reg -> row=(lane>>4)*4+reg, col=lane&15
template<int K, int NT, bool SILU, bool OUT_BF16>
__global__ __launch_bounds__(256) void k_gemm(const bf16* __restrict__ A,
                                              const float* __restrict__ W,
                                              const float* __restrict__ bias,
                                              void* __restrict__ out) {
    __shared__ bf16 A_lds[64][40];    // pad 32->40 to spread banks
    __shared__ bf16 BT_lds[64][40];   // [n][k]
    const int t = threadIdx.x;
    const int mTile = blockIdx.x, nTile = blockIdx.y;
    const int w = t >> 6, lane = t & 63, q = lane >> 4, c = lane & 15;
    const int m0 = mTile * 64, n0 = nTile * 64;

    floatx4 acc[4] = {{0.f,0.f,0.f,0.f},{0.f,0.f,0.f,0.f},{0.f,0.f,0.f,0.f},{0.f,0.f,0.f,0.f}};

    const int ar = t >> 2, achunk = t & 3;   // A staging: row, 16B chunk
    const int bn = t & 63, bkc = t >> 6;     // B staging: local n, k-chunk (8 k's)

    for (int k0 = 0; k0 < K; k0 += 32) {
        // stage A tile: 2048 bf16, 8 per thread, 16B vector load+store
        bf16x8 av = *(const bf16x8*)&A[(size_t)(m0 + ar) * K + k0 + achunk * 8];
        *(bf16x8*)&A_lds[ar][achunk * 8] = av;
        // stage B tile transposed, f32 -> bf16 (coalesced along n per kk)
        bf16x8 bv;
        #pragma unroll
        for (int kk = 0; kk < 8; ++kk)
            bv[kk] = (bf16)W[(size_t)(k0 + bkc * 8 + kk) * NT + n0 + bn];
        *(bf16x8*)&BT_lds[bn][bkc * 8] = bv;
        __syncthreads();

        bf16x8 bfrag = *(const bf16x8*)&BT_lds[w * 16 + c][q * 8];
        #pragma unroll
        for (int mi = 0; mi < 4; ++mi) {
            bf16x8 afrag = *(const bf16x8*)&A_lds[mi * 16 + c][q * 8];
            acc[mi] = __builtin_amdgcn_mfma_f32_16x16x32_bf16(afrag, bfrag, acc[mi], 0, 0, 0);
        }
        __syncthreads();
    }

    const int col = n0 + w * 16 + c;
    const float b = bias[col];
    #pragma unroll
    for (int mi = 0; mi < 4; ++mi) {
        #pragma unroll
        for (int r = 0; r < 4; ++r) {
            int row = m0 + mi * 16 + q * 4 + r;
            float v = acc[mi][r] + b;
            if (SILU) v = v / (1.0f + expf(-v));
            if (OUT_BF16) ((bf16*)out)[(size_t)row * NT + col] = (bf16)v;
            else          ((float*)out)[(size_t)row * NT + col] = v;
        }
    }
}

// ---------- 4: L2 normalize rows + empty-row zeroing ----------
__global__ void k_norm(const float* __restrict__ h3, const int* __restrict__ empty,
                       float* __restrict__ out) {
    int i = blockIdx.x;
    int t = threadIdx.x;              // 0..127 (2 waves)
    float v = h3[i * D_EMB + t];
    float ss = v * v;
    #pragma unroll
    for (int off = 32; off >= 1; off >>= 1) ss += __shfl_down(ss, off);
    __shared__ float sred[2];
    if ((t & 63) == 0) sred[t >> 6] = ss;
    __syncthreads();
    float tot = sred[0] + sred[1];
    // ref: x / max(||x||, 1e-16) applied twice; idempotent for ||x|| > eps
    float scale = 1.0f / fmaxf(sqrtf(tot), 1e-16f);
    out[i * D_EMB + t] = empty[i] ? 0.f : v * scale;
}

extern "C" void kernel_launch(void* const* d_in, const int* in_sizes, int n_in,
                              void* d_out, int out_size, void* d_ws, size_t ws_size,
                              hipStream_t stream) {
    const float* ad = (const float*)d_in[0];
    const int*   user = (const int*)d_in[1];
    const int*   ts   = (const int*)d_in[2];
    const int*   clk  = (const int*)d_in[3];
    const float* W1 = (const float*)d_in[4];
    const float* b1 = (const float*)d_in[5];
    const float* W2 = (const float*)d_in[6];
    const float* b2 = (const float*)d_in[7];
    const float* W3 = (const float*)d_in[8];
    const float* b3 = (const float*)d_in[9];
    float* out = (float*)d_out;
    (void)in_sizes; (void)n_in; (void)out_size; (void)ws_size;

    char* ws = (char*)d_ws;
    size_t off = 0;
    auto alloc = [&](size_t bytes) -> void* {
        void* p = ws + off;
        off += (bytes + 255) & ~(size_t)255;
        return p;
    };
    bf16*  hist  = (bf16*) alloc((size_t)N_ROWS * D_EMB * 2);   // 2 MB
    bf16*  h1    = (bf16*) alloc((size_t)N_ROWS * H1_DIM * 2);  // 8 MB
    bf16*  h2    = (bf16*) alloc((size_t)N_ROWS * H2_DIM * 2);  // 4 MB
    float* h3    = (float*)alloc((size_t)N_ROWS * D_EMB * 4);   // 4 MB
    int*   empty = (int*)  alloc((size_t)N_ROWS * 4);
    int*   meta  = (int*)  alloc((size_t)2 * N_USERS * 4);      // count | cursor
    int*   count  = meta;
    int*   cursor = meta + N_USERS;
    int*   offs   = (int*)alloc((size_t)N_USERS * 4);
    int*   item_ts  = (int*)alloc((size_t)N_ROWS * 4);
    int*   item_idx = (int*)alloc((size_t)N_ROWS * 4);

    // ws is poisoned to 0xAA before every call: zero the atomics region.
    hipMemsetAsync(meta, 0, 2 * N_USERS * sizeof(int), stream);

    k_count  <<<dim3(N_ROWS / 256), dim3(256), 0, stream>>>(user, clk, count);
    k_scan   <<<dim3(1),            dim3(512), 0, stream>>>(count, offs, cursor);
    k_scatter<<<dim3(N_ROWS / 256), dim3(256), 0, stream>>>(user, ts, clk, cursor, item_ts, item_idx);
    k_history<<<dim3(N_ROWS),       dim3(128), 0, stream>>>(user, ts, offs, count, item_ts, item_idx,
                                                            ad, hist, empty);
    k_gemm<D_EMB,  H1_DIM, true,  true ><<<dim3(N_ROWS/64, H1_DIM/64), dim3(256), 0, stream>>>(hist, W1, b1, h1);
    k_gemm<H1_DIM, H2_DIM, true,  true ><<<dim3(N_ROWS/64, H2_DIM/64), dim3(256), 0, stream>>>(h1,   W2, b2, h2);
    k_gemm<H2_DIM, D_EMB,  false, false><<<dim3(N_ROWS/64, D_EMB/64),  dim3(256), 0, stream>>>(h2,   W3, b3, h3);
    k_norm   <<<dim3(N_ROWS),       dim3(128), 0, stream>>>(h3, empty, out);
}

// Round 2
// 113.592 us; speedup vs baseline: 1.1484x; 1.1484x over previous
//
#include <hip/hip_runtime.h>
#include <hip/hip_bf16.h>
#include <math.h>

// UserHistoryTower on MI355X — 2-dispatch fused version.
//
// Dispatch 1 (k_prep, grid 225 x 1024):
//   block 0:   per-user clicked lists: LDS count -> LDS scan -> LDS-cursor scatter
//   blocks 1+: repack W1/W2/W3 (f32 [K][N]) into bf16 MFMA B-fragment order:
//              Wp[((n/16)*(K/32) + k/32)*512 + lane*8 + j] = W[k][n]
//              with lane=(q<<4)|c, k=k0+q*8+j, n=16f+c  -> fused kernel B-loads
//              are lane-contiguous 16B global loads (1 KB/wave, fully coalesced).
// Dispatch 2 (k_fused, grid 256 x 512): each block owns 32 rows:
//   history gather (mean of user's earlier clicked ad rows)
//   -> L1 (128->512, SiLU) -> L2 (512->256, SiLU) -> L3 (256->128)
//   -> row L2-normalize + empty-row zero -> d_out.
//   All activations stay in LDS (59 KB, phases aliased); weights stream from L2.
// MFMA 16x16x32 bf16; layouts HW-verified (round-1 kernel passed with them):
//   A: lane holds A[m=c][k=q*8+j]; B: B[k=q*8+j][n=c]; C/D: row=q*4+r, col=c.

#define N_ROWS  8192
#define D_EMB   128
#define H1_DIM  512
#define H2_DIM  256
#define N_USERS 512

typedef __bf16 bf16;
typedef __bf16 bf16x2 __attribute__((ext_vector_type(2)));
typedef __bf16 bf16x8 __attribute__((ext_vector_type(8)));
typedef float  floatx4 __attribute__((ext_vector_type(4)));

// ---------------- dispatch 1: preprocess + weight repack ----------------

__device__ __forceinline__ void pack_one(int e, int K, int N,
                                         const float* __restrict__ W,
                                         bf16* __restrict__ out) {
    int blk = e >> 9, r = e & 511;          // 512 elems per (frag,chunk) block
    int l = r >> 3, j = r & 7;              // lane, elem-in-lane
    int qq = l >> 4, cc = l & 15;
    int chunks = K >> 5;                    // K/32 (compile-time at call sites)
    int f = blk / chunks, k0c = blk - f * chunks;
    int k = k0c * 32 + qq * 8 + j;
    int n = f * 16 + cc;
    out[e] = (bf16)W[(size_t)k * N + n];
}

__global__ __launch_bounds__(1024) void k_prep(
    const int* __restrict__ user, const int* __restrict__ ts,
    const int* __restrict__ clk,
    const float* __restrict__ W1, const float* __restrict__ W2,
    const float* __restrict__ W3,
    bf16* __restrict__ Wp1, bf16* __restrict__ Wp2, bf16* __restrict__ Wp3,
    int* __restrict__ g_offs, int* __restrict__ g_cnt,
    int2* __restrict__ g_items)
{
    const int bid = blockIdx.x, t = threadIdx.x;
    if (bid > 0) {
        int e = (bid - 1) * 1024 + t;       // 0 .. 229375
        if (e < 65536)       pack_one(e,          128, 512, W1, Wp1);
        else if (e < 196608) pack_one(e -  65536, 512, 256, W2, Wp2);
        else                 pack_one(e - 196608, 256, 128, W3, Wp3);
        return;
    }
    // ---- block 0: count -> scan -> scatter (all in one block via LDS) ----
    __shared__ int s_val[N_USERS];
    __shared__ int s_cur[N_USERS];
    if (t < N_USERS) s_val[t] = 0;
    __syncthreads();
    for (int j = t; j < N_ROWS; j += 1024)
        if (clk[j]) atomicAdd(&s_val[user[j]], 1);
    __syncthreads();
    int c0 = (t < N_USERS) ? s_val[t] : 0;
    for (int d = 1; d < N_USERS; d <<= 1) {
        int v = 0;
        if (t < N_USERS && t >= d) v = s_val[t - d];
        __syncthreads();
        if (t < N_USERS) s_val[t] += v;
        __syncthreads();
    }
    if (t < N_USERS) {
        int off = s_val[t] - c0;            // exclusive prefix
        g_offs[t] = off;
        g_cnt[t]  = c0;
        s_cur[t]  = off;
    }
    __syncthreads();
    for (int j = t; j < N_ROWS; j += 1024)
        if (clk[j]) {
            int p = atomicAdd(&s_cur[user[j]], 1);
            g_items[p] = make_int2(ts[j], j);   // (timestamp, row index)
        }
}

// ---------------- dispatch 2: fused history + MLP + norm ----------------

__device__ __forceinline__ floatx4 mfma16(bf16x8 a, bf16x8 b, floatx4 c) {
    return __builtin_amdgcn_mfma_f32_16x16x32_bf16(a, b, c, 0, 0, 0);
}

__global__ __launch_bounds__(512) void k_fused(
    const int* __restrict__ user, const int* __restrict__ ts,
    const float* __restrict__ ad,
    const int* __restrict__ g_offs, const int* __restrict__ g_cnt,
    const int2* __restrict__ g_items,
    const bf16* __restrict__ Wp1, const bf16* __restrict__ Wp2,
    const bf16* __restrict__ Wp3,
    const float* __restrict__ b1, const float* __restrict__ b2,
    const float* __restrict__ b3,
    float* __restrict__ out)
{
    // LDS plan (59 KB): Ah[32][136] | H1[32][520] | H2[32][264] | empty[32]
    // O[32][132] aliases Ah+H1-head (both dead when O is written).
    __shared__ __align__(16) char smem[59008];
    bf16 (*Ah)[136] = (bf16(*)[136])smem;                    //  8704 B
    bf16 (*H1)[520] = (bf16(*)[520])(smem + 8704);           // 33280 B
    bf16 (*H2)[264] = (bf16(*)[264])(smem + 8704 + 33280);   // 16896 B
    float (*O)[132] = (float(*)[132])smem;                   // 16896 B (alias)
    int* s_empty    = (int*)(smem + 58880);                  //   128 B

    const int t = threadIdx.x;
    const int w = t >> 6, lane = t & 63;
    const int q = lane >> 4, c = lane & 15;
    const int m0 = blockIdx.x * 32;

    // ---- history: wave w handles rows w*4 .. w*4+3; lane covers 2 dims ----
    {
        const int d0 = lane * 2;
        for (int rr = 0; rr < 4; ++rr) {
            const int r32 = w * 4 + rr;
            const int i = m0 + r32;
            const int u = user[i], myts = ts[i];     // broadcast loads
            const int beg = g_offs[u], cnt = g_cnt[u];
            float a0 = 0.f, a1 = 0.f;
            int m = 0;
            for (int p = beg; p < beg + cnt; ++p) {
                int2 it = g_items[p];                // broadcast 8B load
                if (it.x < myts) {                   // strict: matches ts_i > ts_j
                    const float2 v = *(const float2*)(ad + (size_t)it.y * D_EMB + d0);
                    a0 += v.x; a1 += v.y; ++m;
                }
            }
            float inv = m ? 1.f / (float)m : 0.f;
            bf16x2 hv; hv[0] = (bf16)(a0 * inv); hv[1] = (bf16)(a1 * inv);
            *(bf16x2*)&Ah[r32][d0] = hv;
            if (lane == 0) s_empty[r32] = (m == 0);
        }
    }
    __syncthreads();

    // ---- L1: 128 -> 512, SiLU. Wave owns cols [w*64, w*64+64) ----
    {
        floatx4 acc[4][2];
        #pragma unroll
        for (int cf = 0; cf < 4; ++cf)
            #pragma unroll
            for (int mi = 0; mi < 2; ++mi)
                acc[cf][mi] = (floatx4){0.f, 0.f, 0.f, 0.f};
        #pragma unroll
        for (int k0c = 0; k0c < 4; ++k0c) {
            bf16x8 a0 = *(const bf16x8*)&Ah[c][k0c * 32 + q * 8];
            bf16x8 a1 = *(const bf16x8*)&Ah[16 + c][k0c * 32 + q * 8];
            #pragma unroll
            for (int cf = 0; cf < 4; ++cf) {
                bf16x8 b = *(const bf16x8*)&Wp1[(((w * 4 + cf) * 4 + k0c) * 64 + lane) * 8];
                acc[cf][0] = mfma16(a0, b, acc[cf][0]);
                acc[cf][1] = mfma16(a1, b, acc[cf][1]);
            }
        }
        #pragma unroll
        for (int cf = 0; cf < 4; ++cf) {
            const int col = w * 64 + cf * 16 + c;
            const float bb = b1[col];
            #pragma unroll
            for (int mi = 0; mi < 2; ++mi)
                #pragma unroll
                for (int r = 0; r < 4; ++r) {
                    float v = acc[cf][mi][r] + bb;
                    v = v / (1.f + __expf(-v));          // SiLU
                    H1[mi * 16 + q * 4 + r][col] = (bf16)v;
                }
        }
    }
    __syncthreads();

    // ---- L2: 512 -> 256, SiLU. Wave owns cols [w*32, w*32+32) ----
    {
        floatx4 acc[2][2];
        #pragma unroll
        for (int cf = 0; cf < 2; ++cf)
            #pragma unroll
            for (int mi = 0; mi < 2; ++mi)
                acc[cf][mi] = (floatx4){0.f, 0.f, 0.f, 0.f};
        #pragma unroll 4
        for (int k0c = 0; k0c < 16; ++k0c) {
            bf16x8 a0 = *(const bf16x8*)&H1[c][k0c * 32 + q * 8];
            bf16x8 a1 = *(const bf16x8*)&H1[16 + c][k0c * 32 + q * 8];
            #pragma unroll
            for (int cf = 0; cf < 2; ++cf) {
                bf16x8 b = *(const bf16x8*)&Wp2[(((w * 2 + cf) * 16 + k0c) * 64 + lane) * 8];
                acc[cf][0] = mfma16(a0, b, acc[cf][0]);
                acc[cf][1] = mfma16(a1, b, acc[cf][1]);
            }
        }
        #pragma unroll
        for (int cf = 0; cf < 2; ++cf) {
            const int col = w * 32 + cf * 16 + c;
            const float bb = b2[col];
            #pragma unroll
            for (int mi = 0; mi < 2; ++mi)
                #pragma unroll
                for (int r = 0; r < 4; ++r) {
                    float v = acc[cf][mi][r] + bb;
                    v = v / (1.f + __expf(-v));
                    H2[mi * 16 + q * 4 + r][col] = (bf16)v;
                }
        }
    }
    __syncthreads();

    // ---- L3: 256 -> 128 (no act). Wave owns cols [w*16, w*16+16) ----
    {
        floatx4 acc0 = (floatx4){0.f, 0.f, 0.f, 0.f};
        floatx4 acc1 = (floatx4){0.f, 0.f, 0.f, 0.f};
        #pragma unroll
        for (int k0c = 0; k0c < 8; ++k0c) {
            bf16x8 a0 = *(const bf16x8*)&H2[c][k0c * 32 + q * 8];
            bf16x8 a1 = *(const bf16x8*)&H2[16 + c][k0c * 32 + q * 8];
            bf16x8 b = *(const bf16x8*)&Wp3[((w * 8 + k0c) * 64 + lane) * 8];
            acc0 = mfma16(a0, b, acc0);
            acc1 = mfma16(a1, b, acc1);
        }
        const int col = w * 16 + c;
        const float bb = b3[col];
        #pragma unroll
        for (int r = 0; r < 4; ++r) {
            O[q * 4 + r][col]      = acc0[r] + bb;
            O[16 + q * 4 + r][col] = acc1[r] + bb;
        }
    }
    __syncthreads();

    // ---- L2-normalize rows + empty-zero, write out ----
    {
        const int row = t >> 4, s = t & 15;          // 16 threads/row, 8 cols each
        float v[8];
        const float* orow = &O[row][s * 8];
        float ss = 0.f;
        #pragma unroll
        for (int j = 0; j < 8; ++j) { v[j] = orow[j]; ss += v[j] * v[j]; }
        ss += __shfl_xor(ss, 1);
        ss += __shfl_xor(ss, 2);
        ss += __shfl_xor(ss, 4);
        ss += __shfl_xor(ss, 8);
        // x/max(||x||,1e-16) twice == once (||x/||x|| || == 1); empty rows -> 0
        float scale = s_empty[row] ? 0.f : 1.f / fmaxf(sqrtf(ss), 1e-16f);
        float4 o0 = {v[0] * scale, v[1] * scale, v[2] * scale, v[3] * scale};
        float4 o1 = {v[4] * scale, v[5] * scale, v[6] * scale, v[7] * scale};
        float* dst = out + (size_t)(m0 + row) * D_EMB + s * 8;
        *(float4*)dst       = o0;
        *(float4*)(dst + 4) = o1;
    }
}

// ---------------- launcher ----------------

extern "C" void kernel_launch(void* const* d_in, const int* in_sizes, int n_in,
                              void* d_out, int out_size, void* d_ws, size_t ws_size,
                              hipStream_t stream) {
    const float* ad   = (const float*)d_in[0];
    const int*   user = (const int*)d_in[1];
    const int*   ts   = (const int*)d_in[2];
    const int*   clk  = (const int*)d_in[3];
    const float* W1 = (const float*)d_in[4];
    const float* b1 = (const float*)d_in[5];
    const float* W2 = (const float*)d_in[6];
    const float* b2 = (const float*)d_in[7];
    const float* W3 = (const float*)d_in[8];
    const float* b3 = (const float*)d_in[9];
    float* out = (float*)d_out;
    (void)in_sizes; (void)n_in; (void)out_size; (void)ws_size;

    char* ws = (char*)d_ws;
    bf16* Wp1     = (bf16*)(ws);                    // 131072 B
    bf16* Wp2     = (bf16*)(ws + 131072);           // 262144 B
    bf16* Wp3     = (bf16*)(ws + 393216);           //  65536 B
    int*  g_offs  = (int*) (ws + 458752);           //   2048 B
    int*  g_cnt   = (int*) (ws + 460800);           //   2048 B
    int2* g_items = (int2*)(ws + 462848);           //  65536 B

    k_prep <<<dim3(225), dim3(1024), 0, stream>>>(user, ts, clk, W1, W2, W3,
                                                  Wp1, Wp2, Wp3,
                                                  g_offs, g_cnt, g_items);
    k_fused<<<dim3(N_ROWS / 32), dim3(512), 0, stream>>>(user, ts, ad,
                                                         g_offs, g_cnt, g_items,
                                                         Wp1, Wp2, Wp3,
                                                         b1, b2, b3, out);
}